// Round 10
// baseline (141.978 us; speedup 1.0000x reference)
//
#include <hip/hip_runtime.h>

#define N_VARS   50000
#define N_EDGES  400000
#define HID      128
#define MTILES   (N_VARS / 16)                  // 3125
#define MPB      4                              // m-tiles per gemm block
#define GEMM_BLOCKS ((MTILES + MPB - 1) / MPB)  // 782
#define NBKT     196                            // coarse buckets: dst >> 8
#define NDST_PAD (NBKT * 256)                   // 50176
#define CAP      64                             // fine bucket capacity (max deg ~42)
#define CAP2     48                             // per-(edge-block,bucket) capacity (mean 10.4)
#define ABLOCKS  391                            // ceil(400000 / 1024)

// ws byte layout (no region needs pre-initialization — poison-safe):
//   y1f8 (fp8) | y2b (bf16) | srcs (ushort) | blkcnt (int) | cursor (int) | coarse2 (int)
#define Y1_B0   0
#define Y1_SZ   (N_VARS * HID)                  // 6,400,000
#define Y2_B0   (Y1_B0 + Y1_SZ)
#define Y2_SZ   (N_VARS * HID * 2)              // 12,800,000
#define SRC_B0  (Y2_B0 + Y2_SZ)
#define SRC_SZ  (NDST_PAD * CAP * 2)            // 6,422,528
#define BLK_B0  (SRC_B0 + SRC_SZ)
#define BLK_SZ  (ABLOCKS * NBKT * 4)            // 306,544
#define CUR_B0  (BLK_B0 + BLK_SZ)
#define CUR_SZ  (NDST_PAD * 4)                  // 200,704
#define CO_B0   (CUR_B0 + CUR_SZ)               // coarse2: 391*196*48*4 = 14.7 MB

typedef __attribute__((ext_vector_type(8))) short bf16x8;
typedef __attribute__((ext_vector_type(4))) float f32x4;
typedef __attribute__((ext_vector_type(2))) float f32x2;

__device__ __forceinline__ unsigned short f2bf(float f) {
    unsigned u = __builtin_bit_cast(unsigned, f);
    unsigned r = u + 0x7fffu + ((u >> 16) & 1u);  // RNE
    return (unsigned short)(r >> 16);
}

__device__ __forceinline__ bf16x8 cvt8(float4 a0, float4 a1) {
    bf16x8 r;
    r[0] = (short)f2bf(a0.x); r[1] = (short)f2bf(a0.y);
    r[2] = (short)f2bf(a0.z); r[3] = (short)f2bf(a0.w);
    r[4] = (short)f2bf(a1.x); r[5] = (short)f2bf(a1.y);
    r[6] = (short)f2bf(a1.z); r[7] = (short)f2bf(a1.w);
    return r;
}

// ---------------------------------------------------------------------------
// Fused gemm + binA (no prep kernel; nothing in ws needs pre-zeroing).
//
// GEMM blocks: W fragments loaded+converted inline from global W (L2-resident,
// once per block, amortized over MPB=4 m-tiles). Operand-swapped MFMA
// (wb as A) -> D[n][v]: lane = v, 4 consecutive n per acc reg.
//   wv<2 : y1 -> fp8 e4m3 packed dword store
//   wv>=2: y2 -> bf16 in ws (uint2 store), UNSCALED; gather applies deg.
//
// binA blocks: bin 1024 undirected edges into per-(block,bucket) STATIC
// regions coarse2[bA][bkt][CAP2] — LDS counts only, zero global atomics.
// blkcnt[bA][bkt] = entry count (clamped; P(>CAP2) ~ 1e-15/cell).
// ---------------------------------------------------------------------------
__global__ __launch_bounds__(256) void gemm_binA_kernel(
    const float* __restrict__ x, const float* __restrict__ W,
    const int* __restrict__ e,
    unsigned char* __restrict__ y1f8, unsigned short* __restrict__ y2b,
    int* __restrict__ blkcnt, int* __restrict__ coarse2) {
    __shared__ int cnt[NBKT];
    const int t = threadIdx.x;

    if (blockIdx.x < GEMM_BLOCKS) {
        // ---------------- GEMM ----------------
        const int lane = t & 63;
        const int wv   = t >> 6;
        const int ml   = lane & 15;
        const int quad = lane >> 4;

        // B fragments for my 4 n-tiles, converted inline from fp32 W.
        bf16x8 bfrag[4][4];
#pragma unroll
        for (int i = 0; i < 4; ++i) {
            const int n = (wv * 4 + i) * 16 + ml;
            const float* wrow = (n < HID) ? (W + (size_t)n * 256)
                                          : (W + (size_t)(n - HID) * 256 + HID);
#pragma unroll
            for (int kc = 0; kc < 4; ++kc) {
                const float4* w4 = (const float4*)(wrow + kc * 32 + quad * 8);
                bfrag[i][kc] = cvt8(w4[0], w4[1]);
            }
        }

#pragma unroll
        for (int mi = 0; mi < MPB; ++mi) {
            const int mt = blockIdx.x * MPB + mi;
            if (mt >= MTILES) break;
            const int v = mt * 16 + ml;

            bf16x8 afrag[4];
#pragma unroll
            for (int kc = 0; kc < 4; ++kc) {
                const float4* ap = (const float4*)(x + (size_t)v * HID + kc * 32 + quad * 8);
                afrag[kc] = cvt8(ap[0], ap[1]);
            }

            f32x4 acc[4];
#pragma unroll
            for (int i = 0; i < 4; ++i) acc[i] = f32x4{0.f, 0.f, 0.f, 0.f};
#pragma unroll
            for (int kc = 0; kc < 4; ++kc)
#pragma unroll
                for (int i = 0; i < 4; ++i)  // swapped operands -> D[n][v]
                    acc[i] = __builtin_amdgcn_mfma_f32_16x16x32_bf16(bfrag[i][kc], afrag[kc], acc[i], 0, 0, 0);

            if (wv < 2) {
#pragma unroll
                for (int i = 0; i < 4; ++i) {
                    int w = __builtin_amdgcn_cvt_pk_fp8_f32(acc[i][0], acc[i][1], 0, false);
                    w     = __builtin_amdgcn_cvt_pk_fp8_f32(acc[i][2], acc[i][3], w, true);
                    *(int*)(y1f8 + (size_t)v * HID + wv * 64 + i * 16 + quad * 4) = w;
                }
            } else {
#pragma unroll
                for (int i = 0; i < 4; ++i) {
                    uint2 p;
                    p.x = (unsigned)f2bf(acc[i][0]) | ((unsigned)f2bf(acc[i][1]) << 16);
                    p.y = (unsigned)f2bf(acc[i][2]) | ((unsigned)f2bf(acc[i][3]) << 16);
                    *(uint2*)(y2b + (size_t)v * HID + (wv - 2) * 64 + i * 16 + quad * 4) = p;
                }
            }
        }
    } else {
        // ---------------- binA ----------------
        const int bA = blockIdx.x - GEMM_BLOCKS;
        for (int i = t; i < NBKT; i += 256) cnt[i] = 0;
        __syncthreads();

        int e0[4], e1[4], nb = 0;
        const int b0 = (bA * 256 + t) * 4;
        if (bA < ABLOCKS - 1) {
            int4 A = *(const int4*)(e + b0);
            int4 B = *(const int4*)(e + N_EDGES + b0);
            e0[0] = A.x; e0[1] = A.y; e0[2] = A.z; e0[3] = A.w;
            e1[0] = B.x; e1[1] = B.y; e1[2] = B.z; e1[3] = B.w;
            nb = 4;
        } else {
            for (int j = 0; j < 4; ++j)
                if (b0 + j < N_EDGES) { e0[nb] = e[b0 + j]; e1[nb] = e[N_EDGES + b0 + j]; ++nb; }
        }

        int* myregion = coarse2 + (size_t)bA * NBKT * CAP2;
#pragma unroll 4
        for (int j = 0; j < nb; ++j) {
            int a = e0[j], b = e1[j];
            int bk0 = b >> 8, bk1 = a >> 8;
            int p0  = (a << 8) | (b & 255);
            int p1  = (b << 8) | (a & 255);
            int l0  = atomicAdd(&cnt[bk0], 1);
            if (l0 < CAP2) myregion[bk0 * CAP2 + l0] = p0;
            int l1  = atomicAdd(&cnt[bk1], 1);
            if (l1 < CAP2) myregion[bk1 * CAP2 + l1] = p1;
        }
        __syncthreads();
        for (int i = t; i < NBKT; i += 256) {
            int c = cnt[i];
            blkcnt[bA * NBKT + i] = (c < CAP2) ? c : CAP2;
        }
    }
}

// ---------------------------------------------------------------------------
// binB: one block per coarse bucket (256 dsts). Reads the 391 per-edge-block
// segments for its bucket, builds fine per-dst buckets in LDS (CAP=64,
// 32 KB), streams them out densely, writes cursor (= exact degree).
// ---------------------------------------------------------------------------
__global__ __launch_bounds__(256) void binB_kernel(const int* __restrict__ blkcnt,
                                                   const int* __restrict__ coarse2,
                                                   unsigned short* __restrict__ srcs,
                                                   int* __restrict__ cursor) {
    __shared__ int fcnt[256];
    __shared__ unsigned short fine[256 * CAP];  // 32 KB
    const int t = threadIdx.x, b = blockIdx.x;
    fcnt[t] = 0;
    __syncthreads();

    for (int s = t; s < ABLOCKS; s += 256) {
        int c = blkcnt[s * NBKT + b];
        const int* seg = coarse2 + (size_t)(s * NBKT + b) * CAP2;
        for (int i = 0; i < c; ++i) {
            int p = seg[i];
            int dl = p & 255;
            int pos = atomicAdd(&fcnt[dl], 1);
            if (pos < CAP) fine[dl * CAP + pos] = (unsigned short)(p >> 8);
        }
    }
    __syncthreads();

    const uint4* fs = (const uint4*)fine;
    uint4* gs = (uint4*)(srcs + (size_t)b * 256 * CAP);
#pragma unroll
    for (int k = 0; k < 8; ++k) gs[k * 256 + t] = fs[k * 256 + t];  // 32 KB
    cursor[b * 256 + t] = fcnt[t];
}

// ---------------------------------------------------------------------------
// gather: out[v] = deg[v]*bf16dec(y2b[v]) + sum_{src in bucket[v]} fp8dec(y1f8[src])
// 8 lanes per var (uint4 = 16 fp8), 32 vars per block, 4-deep ILP.
// out is written exactly once (no RMW).
// ---------------------------------------------------------------------------
__global__ __launch_bounds__(256) void gather_kernel(const unsigned char* __restrict__ y1f8,
                                                     const unsigned short* __restrict__ y2b,
                                                     const int* __restrict__ cursor,
                                                     const unsigned short* __restrict__ srcs,
                                                     float* __restrict__ out) {
    const int t    = threadIdx.x;
    const int v    = blockIdx.x * 32 + (t >> 3);
    const int lane = t & 7;
    if (v >= N_VARS) return;
    const int c = cursor[v];
    const int n = (c < CAP) ? c : CAP;
    const unsigned short* bucket = srcs + (size_t)v * CAP;

    const uint4* base = (const uint4*)y1f8;  // row stride = 8 uint4 (128 B)
    float acc[16];
#pragma unroll
    for (int i = 0; i < 16; ++i) acc[i] = 0.f;

    auto accum = [&](uint4 a) {
        int u[4] = {(int)a.x, (int)a.y, (int)a.z, (int)a.w};
#pragma unroll
        for (int w = 0; w < 4; ++w) {
            f32x2 lo = __builtin_amdgcn_cvt_pk_f32_fp8(u[w], false);
            f32x2 hi = __builtin_amdgcn_cvt_pk_f32_fp8(u[w], true);
            acc[4 * w + 0] += lo[0];
            acc[4 * w + 1] += lo[1];
            acc[4 * w + 2] += hi[0];
            acc[4 * w + 3] += hi[1];
        }
    };

    int j = 0;
    for (; j + 4 <= n; j += 4) {
        int s0 = bucket[j + 0], s1 = bucket[j + 1];
        int s2 = bucket[j + 2], s3 = bucket[j + 3];
        uint4 a0 = base[(size_t)s0 * 8 + lane];
        uint4 a1 = base[(size_t)s1 * 8 + lane];
        uint4 a2 = base[(size_t)s2 * 8 + lane];
        uint4 a3 = base[(size_t)s3 * 8 + lane];
        accum(a0); accum(a1); accum(a2); accum(a3);
    }
    for (; j < n; ++j) accum(base[(size_t)bucket[j] * 8 + lane]);

    // y2 (bf16) decode + deg scale, single write of out
    const uint4* y2p = (const uint4*)(y2b + (size_t)v * HID) + lane * 2;
    uint4 w0 = y2p[0], w1 = y2p[1];
    unsigned uu[8] = {w0.x, w0.y, w0.z, w0.w, w1.x, w1.y, w1.z, w1.w};
    const float dg = (float)c;
    float4* op = (float4*)(out + (size_t)v * HID + lane * 16);
#pragma unroll
    for (int q = 0; q < 4; ++q) {
        float b0 = __builtin_bit_cast(float, uu[2 * q] << 16);
        float b1 = __builtin_bit_cast(float, uu[2 * q] & 0xffff0000u);
        float b2 = __builtin_bit_cast(float, uu[2 * q + 1] << 16);
        float b3 = __builtin_bit_cast(float, uu[2 * q + 1] & 0xffff0000u);
        float4 o = {dg * b0 + acc[4 * q + 0], dg * b1 + acc[4 * q + 1],
                    dg * b2 + acc[4 * q + 2], dg * b3 + acc[4 * q + 3]};
        op[q] = o;
    }
}

extern "C" void kernel_launch(void* const* d_in, const int* in_sizes, int n_in,
                              void* d_out, int out_size, void* d_ws, size_t ws_size,
                              hipStream_t stream) {
    const float* x = (const float*)d_in[0];
    const float* W = (const float*)d_in[1];
    const int*   e = (const int*)d_in[2];
    float* out = (float*)d_out;

    unsigned char* wsb = (unsigned char*)d_ws;
    unsigned char*  y1f8   = wsb + Y1_B0;
    unsigned short* y2b    = (unsigned short*)(wsb + Y2_B0);
    unsigned short* srcs   = (unsigned short*)(wsb + SRC_B0);
    int*            blkcnt = (int*)(wsb + BLK_B0);
    int*            cursor = (int*)(wsb + CUR_B0);
    int*            coarse2 = (int*)(wsb + CO_B0);

    gemm_binA_kernel<<<GEMM_BLOCKS + ABLOCKS, 256, 0, stream>>>(
        x, W, e, y1f8, y2b, blkcnt, coarse2);
    binB_kernel<<<NBKT, 256, 0, stream>>>(blkcnt, coarse2, srcs, cursor);
    gather_kernel<<<(N_VARS + 31) / 32, 256, 0, stream>>>(y1f8, y2b, cursor, srcs, out);
}

// Round 11
// 132.368 us; speedup vs baseline: 1.0726x; 1.0726x over previous
//
#include <hip/hip_runtime.h>

#define N_VARS   50000
#define N_EDGES  400000
#define HID      128
#define MTILES   (N_VARS / 16)        // 3125
#define GEMM_BLOCKS ((MTILES + 1) / 2) // 1563 (MPB=2, r9's best)
#define NBKT     196                  // coarse buckets: dst >> 8
#define CCAP     4608                 // coarse capacity (mean 4082, +8 sigma)
#define NDST_PAD (NBKT * 256)         // 50176
#define CAP      64                   // fine bucket capacity (max deg ~42; validated r10)
#define ABLOCKS  391                  // ceil(400000 / 1024)

// ws byte layout:
//   y1f8 (fp8) | y2b (bf16) | wb (bf16 frags) | srcs (ushort) |
//   ints: gcount[NBKT] | cursor[NDST_PAD] | coarse[NBKT*CCAP]
#define Y1_B0   0
#define Y1_SZ   (N_VARS * HID)                  // 6,400,000
#define Y2_B0   (Y1_B0 + Y1_SZ)
#define Y2_SZ   (N_VARS * HID * 2)              // 12,800,000
#define WB_B0   (Y2_B0 + Y2_SZ)
#define WB_SZ   (64 * 64 * 8 * 2)               // 65,536
#define SRC_B0  (WB_B0 + WB_SZ)
#define SRC_SZ  (NDST_PAD * CAP * 2)            // 6,422,528
#define INT_B0  (SRC_B0 + SRC_SZ)               // % 4 == 0

#define I_GCOUNT 0
#define I_CURSOR (I_GCOUNT + NBKT)
#define I_COARSE (I_CURSOR + NDST_PAD)

typedef __attribute__((ext_vector_type(8))) short bf16x8;
typedef __attribute__((ext_vector_type(4))) float f32x4;
typedef __attribute__((ext_vector_type(2))) float f32x2;

__device__ __forceinline__ unsigned short f2bf(float f) {
    unsigned u = __builtin_bit_cast(unsigned, f);
    unsigned r = u + 0x7fffu + ((u >> 16) & 1u);  // RNE
    return (unsigned short)(r >> 16);
}

__device__ __forceinline__ bf16x8 cvt8(float4 a0, float4 a1) {
    bf16x8 r;
    r[0] = (short)f2bf(a0.x); r[1] = (short)f2bf(a0.y);
    r[2] = (short)f2bf(a0.z); r[3] = (short)f2bf(a0.w);
    r[4] = (short)f2bf(a1.x); r[5] = (short)f2bf(a1.y);
    r[6] = (short)f2bf(a1.z); r[7] = (short)f2bf(a1.w);
    return r;
}

// ---------------------------------------------------------------------------
// prep: wb = fragment-ordered bf16 W; zero gcount. (r9 structure, minus
// extra/ovf.) Fragment (nt,kc): n=nt*16+(lane&15), k=kc*32+(lane>>4)*8+j,
// source row: n<128 ? W[n][k] : W[n-128][128+k].
// ---------------------------------------------------------------------------
__global__ __launch_bounds__(256) void prep_kernel(const float* __restrict__ W,
                                                   short* __restrict__ wb,
                                                   int* __restrict__ gcount) {
    int gid = blockIdx.x * 256 + threadIdx.x;
    if (gid < NBKT) gcount[gid] = 0;
    if (gid < 4096) {
        int f = gid >> 6, lane = gid & 63;
        int nt = f >> 2, kc = f & 3;
        int ml = lane & 15, quad = lane >> 4;
        int n = nt * 16 + ml;
        const float* wp = (n < HID) ? (W + (size_t)n * 256)
                                    : (W + (size_t)(n - HID) * 256 + HID);
        wp += kc * 32 + quad * 8;
        const float4* w4 = (const float4*)wp;
        *(bf16x8*)(wb + (size_t)f * 512 + lane * 8) = cvt8(w4[0], w4[1]);
    }
}

// ---------------------------------------------------------------------------
// Fused gemm + binA (r9 structure; y2 now bf16 to ws).
// GEMM: operand-swapped MFMA -> D[n][v]; lane = v, 4 consecutive n per acc.
//   wv<2 : y1 -> fp8 e4m3 packed dword store
//   wv>=2: y2 -> bf16 ws (uint2 store), UNSCALED; gather applies deg.
// binA: LDS-aggregated reservation into dense per-bucket runs of coarse.
// ---------------------------------------------------------------------------
__global__ __launch_bounds__(256) void gemm_binA_kernel(
    const float* __restrict__ x, const short* __restrict__ wb,
    const int* __restrict__ e,
    unsigned char* __restrict__ y1f8, unsigned short* __restrict__ y2b,
    int* __restrict__ gcount, int* __restrict__ coarse) {
    __shared__ int cnt[NBKT];
    __shared__ int base[NBKT];
    const int t = threadIdx.x;

    if (blockIdx.x < GEMM_BLOCKS) {
        // ---------------- GEMM ----------------
        const int lane = t & 63;
        const int wv   = t >> 6;
        const int ml   = lane & 15;
        const int quad = lane >> 4;

        bf16x8 bfrag[4][4];
#pragma unroll
        for (int i = 0; i < 4; ++i)
#pragma unroll
            for (int kc = 0; kc < 4; ++kc)
                bfrag[i][kc] = *(const bf16x8*)(wb + (size_t)((wv * 4 + i) * 4 + kc) * 512 + lane * 8);

#pragma unroll
        for (int mi = 0; mi < 2; ++mi) {
            const int mt = blockIdx.x * 2 + mi;
            if (mt >= MTILES) break;
            const int v = mt * 16 + ml;

            bf16x8 afrag[4];
#pragma unroll
            for (int kc = 0; kc < 4; ++kc) {
                const float4* ap = (const float4*)(x + (size_t)v * HID + kc * 32 + quad * 8);
                afrag[kc] = cvt8(ap[0], ap[1]);
            }

            f32x4 acc[4];
#pragma unroll
            for (int i = 0; i < 4; ++i) acc[i] = f32x4{0.f, 0.f, 0.f, 0.f};
#pragma unroll
            for (int kc = 0; kc < 4; ++kc)
#pragma unroll
                for (int i = 0; i < 4; ++i)  // swapped operands -> D[n][v]
                    acc[i] = __builtin_amdgcn_mfma_f32_16x16x32_bf16(bfrag[i][kc], afrag[kc], acc[i], 0, 0, 0);

            if (wv < 2) {
#pragma unroll
                for (int i = 0; i < 4; ++i) {
                    int w = __builtin_amdgcn_cvt_pk_fp8_f32(acc[i][0], acc[i][1], 0, false);
                    w     = __builtin_amdgcn_cvt_pk_fp8_f32(acc[i][2], acc[i][3], w, true);
                    *(int*)(y1f8 + (size_t)v * HID + wv * 64 + i * 16 + quad * 4) = w;
                }
            } else {
#pragma unroll
                for (int i = 0; i < 4; ++i) {
                    uint2 p;
                    p.x = (unsigned)f2bf(acc[i][0]) | ((unsigned)f2bf(acc[i][1]) << 16);
                    p.y = (unsigned)f2bf(acc[i][2]) | ((unsigned)f2bf(acc[i][3]) << 16);
                    *(uint2*)(y2b + (size_t)v * HID + (wv - 2) * 64 + i * 16 + quad * 4) = p;
                }
            }
        }
    } else {
        // ---------------- binA (r9's dense reservation) ----------------
        const int bA = blockIdx.x - GEMM_BLOCKS;
        for (int i = t; i < NBKT; i += 256) cnt[i] = 0;
        __syncthreads();

        int e0[4], e1[4], nb = 0;
        const int b0 = (bA * 256 + t) * 4;
        if (bA < ABLOCKS - 1) {
            int4 A = *(const int4*)(e + b0);
            int4 B = *(const int4*)(e + N_EDGES + b0);
            e0[0] = A.x; e0[1] = A.y; e0[2] = A.z; e0[3] = A.w;
            e1[0] = B.x; e1[1] = B.y; e1[2] = B.z; e1[3] = B.w;
            nb = 4;
        } else {
            for (int j = 0; j < 4; ++j)
                if (b0 + j < N_EDGES) { e0[nb] = e[b0 + j]; e1[nb] = e[N_EDGES + b0 + j]; ++nb; }
        }

        int bkt[8], lpos[8], pk[8];
#pragma unroll 4
        for (int j = 0; j < nb; ++j) {
            int a = e0[j], b = e1[j];
            bkt[2 * j]      = b >> 8;
            pk[2 * j]       = (a << 8) | (b & 255);
            lpos[2 * j]     = atomicAdd(&cnt[b >> 8], 1);
            bkt[2 * j + 1]  = a >> 8;
            pk[2 * j + 1]   = (b << 8) | (a & 255);
            lpos[2 * j + 1] = atomicAdd(&cnt[a >> 8], 1);
        }
        __syncthreads();
        for (int i = t; i < NBKT; i += 256)
            base[i] = (cnt[i] > 0) ? atomicAdd(&gcount[i], cnt[i]) : 0;
        __syncthreads();

        for (int j = 0; j < 2 * nb; ++j) {
            int p = base[bkt[j]] + lpos[j];
            if (p < CCAP) coarse[bkt[j] * CCAP + p] = pk[j];  // clamp: never trips
        }
    }
}

// ---------------------------------------------------------------------------
// binB (r9's flat-stride form): one block per coarse bucket (256 dsts).
// Fine per-dst buckets in LDS (CAP=64, 32 KB), dense stream-out, cursor=deg.
// ---------------------------------------------------------------------------
__global__ __launch_bounds__(256) void binB_kernel(const int* __restrict__ gcount,
                                                   const int* __restrict__ coarse,
                                                   unsigned short* __restrict__ srcs,
                                                   int* __restrict__ cursor) {
    __shared__ int fcnt[256];
    __shared__ unsigned short fine[256 * CAP];  // 32 KB
    const int t = threadIdx.x, b = blockIdx.x;
    fcnt[t] = 0;
    __syncthreads();

    int n = gcount[b];
    if (n > CCAP) n = CCAP;
    const int* cb = coarse + b * CCAP;

    int i = t;
    int p = (i < n) ? cb[i] : 0;
    while (i < n) {
        int pn = (i + 256 < n) ? cb[i + 256] : 0;   // prefetch next
        int dl = p & 255;
        int pos = atomicAdd(&fcnt[dl], 1);
        if (pos < CAP) fine[dl * CAP + pos] = (unsigned short)(p >> 8);
        p = pn;
        i += 256;
    }
    __syncthreads();

    const uint4* fs = (const uint4*)fine;
    uint4* gs = (uint4*)(srcs + (size_t)b * 256 * CAP);
#pragma unroll
    for (int k = 0; k < 8; ++k) gs[k * 256 + t] = fs[k * 256 + t];  // 32 KB
    cursor[b * 256 + t] = fcnt[t];
}

// ---------------------------------------------------------------------------
// gather: out[v] = deg[v]*bf16dec(y2b[v]) + sum_{src in bucket[v]} fp8dec(y1f8[src])
// 8 lanes per var (uint4 = 16 fp8), 32 vars per block, 4-deep ILP.
// out written exactly once (no RMW).
// ---------------------------------------------------------------------------
__global__ __launch_bounds__(256) void gather_kernel(const unsigned char* __restrict__ y1f8,
                                                     const unsigned short* __restrict__ y2b,
                                                     const int* __restrict__ cursor,
                                                     const unsigned short* __restrict__ srcs,
                                                     float* __restrict__ out) {
    const int t    = threadIdx.x;
    const int v    = blockIdx.x * 32 + (t >> 3);
    const int lane = t & 7;
    if (v >= N_VARS) return;
    const int c = cursor[v];
    const int n = (c < CAP) ? c : CAP;
    const unsigned short* bucket = srcs + (size_t)v * CAP;

    const uint4* base = (const uint4*)y1f8;  // row stride = 8 uint4 (128 B)
    float acc[16];
#pragma unroll
    for (int i = 0; i < 16; ++i) acc[i] = 0.f;

    auto accum = [&](uint4 a) {
        int u[4] = {(int)a.x, (int)a.y, (int)a.z, (int)a.w};
#pragma unroll
        for (int w = 0; w < 4; ++w) {
            f32x2 lo = __builtin_amdgcn_cvt_pk_f32_fp8(u[w], false);
            f32x2 hi = __builtin_amdgcn_cvt_pk_f32_fp8(u[w], true);
            acc[4 * w + 0] += lo[0];
            acc[4 * w + 1] += lo[1];
            acc[4 * w + 2] += hi[0];
            acc[4 * w + 3] += hi[1];
        }
    };

    int j = 0;
    for (; j + 4 <= n; j += 4) {
        int s0 = bucket[j + 0], s1 = bucket[j + 1];
        int s2 = bucket[j + 2], s3 = bucket[j + 3];
        uint4 a0 = base[(size_t)s0 * 8 + lane];
        uint4 a1 = base[(size_t)s1 * 8 + lane];
        uint4 a2 = base[(size_t)s2 * 8 + lane];
        uint4 a3 = base[(size_t)s3 * 8 + lane];
        accum(a0); accum(a1); accum(a2); accum(a3);
    }
    for (; j < n; ++j) accum(base[(size_t)bucket[j] * 8 + lane]);

    // y2 (bf16) decode + deg scale, single write of out
    const uint4* y2p = (const uint4*)(y2b + (size_t)v * HID) + lane * 2;
    uint4 w0 = y2p[0], w1 = y2p[1];
    unsigned uu[8] = {w0.x, w0.y, w0.z, w0.w, w1.x, w1.y, w1.z, w1.w};
    const float dg = (float)c;
    float4* op = (float4*)(out + (size_t)v * HID + lane * 16);
#pragma unroll
    for (int q = 0; q < 4; ++q) {
        float b0 = __builtin_bit_cast(float, uu[2 * q] << 16);
        float b1 = __builtin_bit_cast(float, uu[2 * q] & 0xffff0000u);
        float b2 = __builtin_bit_cast(float, uu[2 * q + 1] << 16);
        float b3 = __builtin_bit_cast(float, uu[2 * q + 1] & 0xffff0000u);
        float4 o = {dg * b0 + acc[4 * q + 0], dg * b1 + acc[4 * q + 1],
                    dg * b2 + acc[4 * q + 2], dg * b3 + acc[4 * q + 3]};
        op[q] = o;
    }
}

extern "C" void kernel_launch(void* const* d_in, const int* in_sizes, int n_in,
                              void* d_out, int out_size, void* d_ws, size_t ws_size,
                              hipStream_t stream) {
    const float* x = (const float*)d_in[0];
    const float* W = (const float*)d_in[1];
    const int*   e = (const int*)d_in[2];
    float* out = (float*)d_out;

    unsigned char* wsb = (unsigned char*)d_ws;
    unsigned char*  y1f8   = wsb + Y1_B0;
    unsigned short* y2b    = (unsigned short*)(wsb + Y2_B0);
    short*          wb     = (short*)(wsb + WB_B0);
    unsigned short* srcs   = (unsigned short*)(wsb + SRC_B0);
    int*            wsi    = (int*)(wsb + INT_B0);
    int*            gcount = wsi + I_GCOUNT;
    int*            cursor = wsi + I_CURSOR;
    int*            coarse = wsi + I_COARSE;

    prep_kernel<<<17, 256, 0, stream>>>(W, wb, gcount);
    gemm_binA_kernel<<<GEMM_BLOCKS + ABLOCKS, 256, 0, stream>>>(
        x, wb, e, y1f8, y2b, gcount, coarse);
    binB_kernel<<<NBKT, 256, 0, stream>>>(gcount, coarse, srcs, cursor);
    gather_kernel<<<(N_VARS + 31) / 32, 256, 0, stream>>>(y1f8, y2b, cursor, srcs, out);
}